// Round 24
// baseline (153.856 us; speedup 1.0000x reference)
//
#include <hip/hip_runtime.h>
#include <math.h>

#define NROWS 32768
#define DDIM 256
#define KEMB 1024

#define OFF_COMMIT 8388608
#define OFF_EMBED  8388609
#define OFF_ENT    8388610
#define OFF_IDX    8388611

// ws float layout: [0..1023] avg_prob sums, [1024] H sum, [1025] sqdiff sum,
// [1026..2049] cnorm, int[2052] worklist counter,
// [4096..266239] cb bf16 hi/lo fragment image (1 MB),
// [266240..) fp16 logits buffer (64 MB), int[WL2_BASE_F..] worklist.
#define WS_IMG_F 4096
#define WS_LG_F  266240
#define WL_CNT   2052
#define WL2_BASE_F (WS_LG_F + 16777216)
#define WL2_CAP  32768

// Magnitude-aware danger/candidate threshold (r22 verified):
//  |m1| < 2040  -> 1.25 ;  |m1| >= 2040 -> 2.5 (fp16 ulp=2 regime).
__device__ inline float danger_thr(float m1) {
  return (fabsf(m1) >= 2040.0f) ? 2.5f : 1.25f;
}

// prevent -ffp-contract=fast from fusing this mul into a following add
#define NOFUSE(x) asm volatile("" : "+v"(x))

typedef __attribute__((ext_vector_type(8))) short bf16x8;
typedef __attribute__((ext_vector_type(16))) float f32x16;
typedef __attribute__((ext_vector_type(4))) _Float16 f16x4;
#define MFMA32(a, b, c) __builtin_amdgcn_mfma_f32_32x32x16_bf16((a), (b), (c), 0, 0, 0)

// round-to-nearest-even fp32 -> bf16 hi + bf16 lo split
__device__ inline void bf16split(float x, unsigned short& h, unsigned short& l) {
  unsigned u = __float_as_uint(x);
  unsigned r = u + 0x7FFFu + ((u >> 16) & 1u);
  h = (unsigned short)(r >> 16);
  float hf = __uint_as_float(r & 0xFFFF0000u);
  float lo = x - hf;  // exact (Sterbenz)
  unsigned ul = __float_as_uint(lo);
  unsigned rl = ul + 0x7FFFu + ((ul >> 16) & 1u);
  l = (unsigned short)(rl >> 16);
}

// ---- fused pre-pass (r10 verified; + worklist counter zero) ----
__global__ __launch_bounds__(256) void vq_pre(const float* __restrict__ cb,
                                              float* __restrict__ ws) {
  const int tid = threadIdx.x;
  if (blockIdx.x == 0 && tid == 0) ((int*)ws)[WL_CNT] = 0;
  if (blockIdx.x < 64) {
    int t = blockIdx.x * 256 + tid;  // [0,16384)
    if (t < 1026) ws[t] = 0.0f;
    int row = t >> 4;  // 0..1023
    int l = t & 15;
    int h = l >> 3, j = l & 7;
    const float* xp = cb + (size_t)row * DDIM + h * 128 + j;
    float x = xp[0];
    float sq = x * x; NOFUSE(sq);
    float r = sq;
#pragma unroll
    for (int tt = 1; tt < 16; ++tt) {
      x = xp[8 * tt];
      sq = x * x; NOFUSE(sq);
      r = r + sq;
    }
    r = r + __shfl_xor(r, 1, 64);
    r = r + __shfl_xor(r, 2, 64);
    r = r + __shfl_xor(r, 4, 64);
    r = r + __shfl_xor(r, 8, 64);
    if (l == 0) ws[1026 + row] = r;
  } else {
    unsigned short* img = (unsigned short*)(ws + WS_IMG_F);
    int t = (blockIdx.x - 64) * 256 + tid;  // [0,32768)
    int kc = t >> 11;
    int ct = (t >> 6) & 31;
    int lane = t & 63;
    int l31 = lane & 31, lhi = lane >> 5;
    const float* src = cb + ((size_t)(ct * 32 + l31) << 8) + kc * 16 + lhi * 8;
    float4 v0 = *(const float4*)(src);
    float4 v1 = *(const float4*)(src + 4);
    bf16x8 hv, lv;
    unsigned short hh, ll;
    bf16split(v0.x, hh, ll); hv[0] = hh; lv[0] = ll;
    bf16split(v0.y, hh, ll); hv[1] = hh; lv[1] = ll;
    bf16split(v0.z, hh, ll); hv[2] = hh; lv[2] = ll;
    bf16split(v0.w, hh, ll); hv[3] = hh; lv[3] = ll;
    bf16split(v1.x, hh, ll); hv[4] = hh; lv[4] = ll;
    bf16split(v1.y, hh, ll); hv[5] = hh; lv[5] = ll;
    bf16split(v1.z, hh, ll); hv[6] = hh; lv[6] = ll;
    bf16split(v1.w, hh, ll); hv[7] = hh; lv[7] = ll;
    size_t f = ((size_t)(kc * 32 + ct) * 2) * 64 + lane;  // hl=0
    *(bf16x8*)(img + f * 8) = hv;
    *(bf16x8*)(img + (f + 64) * 8) = lv;                  // hl=1
  }
}

// ---- GEMM kernel BM=64 (r23 verified, unchanged) ----
__global__ __launch_bounds__(1024, 4) void vq_gemm64(const float* __restrict__ z,
                                                     const unsigned short* __restrict__ img,
                                                     _Float16* __restrict__ lg,
                                                     const float* __restrict__ ws,
                                                     int row_base) {
  __shared__ __align__(16) unsigned char smem[65536];
  unsigned short* zh_s = (unsigned short*)smem;
  unsigned short* zl_s = (unsigned short*)(smem + 32768);
  const int tid = threadIdx.x;
  const int w = tid >> 6;
  const int lane = tid & 63;
  const int l31 = lane & 31, lhi = lane >> 5;
  const int ct0 = w * 2, ct1 = w * 2 + 1;
  const unsigned short* pw = img + lane * 8;
  const float* cnorm = ws + 1026;
  const int nbase = row_base + blockIdx.x * 64;

#pragma unroll
  for (int i = 0; i < 16; ++i) {
    int idx = tid + (i << 10);
    int row = idx >> 8, k = idx & 255;
    float x = z[((size_t)(nbase + row) << 8) + k];
    unsigned short hh, ll;
    bf16split(x, hh, ll);
    int uoff = (row << 8) | ((((k >> 3) ^ row) & 31) << 3) | (k & 7);
    zh_s[uoff] = hh; zl_s[uoff] = ll;
  }
  __syncthreads();

  f32x16 acc00, acc01, acc10, acc11;
#pragma unroll
  for (int e = 0; e < 16; ++e) {
    acc00[e] = 0.0f; acc01[e] = 0.0f; acc10[e] = 0.0f; acc11[e] = 0.0f;
  }

  const unsigned short* p0 = pw + ct0 * 1024;
  const unsigned short* p1 = pw + ct1 * 1024;
  bf16x8 nbh0 = *(const bf16x8*)(p0);
  bf16x8 nbl0 = *(const bf16x8*)(p0 + 512);
  bf16x8 nbh1 = *(const bf16x8*)(p1);
  bf16x8 nbl1 = *(const bf16x8*)(p1 + 512);

#pragma unroll 1
  for (int kc = 0; kc < 16; ++kc) {
    bf16x8 ch0 = nbh0, cl0 = nbl0, ch1 = nbh1, cl1 = nbl1;
    const int kn = (kc + 1) & 15;
    const unsigned short* pk = pw + kn * 32768;
    const unsigned short* q0 = pk + ct0 * 1024;
    const unsigned short* q1 = pk + ct1 * 1024;
    nbh0 = *(const bf16x8*)(q0);
    nbl0 = *(const bf16x8*)(q0 + 512);
    nbh1 = *(const bf16x8*)(q1);
    nbl1 = *(const bf16x8*)(q1 + 512);
    const int au0 = (l31 << 8) | (((((kc << 1) | lhi) ^ l31) & 31) << 3);
    const int au1 = ((32 + l31) << 8) | (((((kc << 1) | lhi) ^ l31) & 31) << 3);
    bf16x8 azh0 = *(const bf16x8*)(zh_s + au0);
    bf16x8 azl0 = *(const bf16x8*)(zl_s + au0);
    bf16x8 azh1 = *(const bf16x8*)(zh_s + au1);
    bf16x8 azl1 = *(const bf16x8*)(zl_s + au1);
    acc00 = MFMA32(azh0, ch0, acc00);
    acc01 = MFMA32(azh0, ch1, acc01);
    acc10 = MFMA32(azh1, ch0, acc10);
    acc11 = MFMA32(azh1, ch1, acc11);
    acc00 = MFMA32(azh0, cl0, acc00);
    acc01 = MFMA32(azh0, cl1, acc01);
    acc10 = MFMA32(azh1, cl0, acc10);
    acc11 = MFMA32(azh1, cl1, acc11);
    acc00 = MFMA32(azl0, ch0, acc00);
    acc01 = MFMA32(azl0, ch1, acc01);
    acc10 = MFMA32(azl1, ch0, acc10);
    acc11 = MFMA32(azl1, ch1, acc11);
  }

  const float cn0 = cnorm[ct0 * 32 + l31];
  const float cn1 = cnorm[ct1 * 32 + l31];
  _Float16* lrow0 = lg + (size_t)(blockIdx.x * 64) * 1024;
  _Float16* lrow1 = lrow0 + (size_t)32 * 1024;
#pragma unroll
  for (int reg = 0; reg < 16; ++reg) {
    int ro = (reg & 3) + 8 * ((reg >> 2) & 1) + 16 * (reg >> 3) + 4 * lhi;
    lrow0[(size_t)ro * 1024 + ct0 * 32 + l31] =
        (_Float16)(200.0f * acc00[reg] - 100.0f * cn0);
    lrow0[(size_t)ro * 1024 + ct1 * 32 + l31] =
        (_Float16)(200.0f * acc01[reg] - 100.0f * cn1);
    lrow1[(size_t)ro * 1024 + ct0 * 32 + l31] =
        (_Float16)(200.0f * acc10[reg] - 100.0f * cn0);
    lrow1[(size_t)ro * 1024 + ct1 * 32 + l31] =
        (_Float16)(200.0f * acc11[reg] - 100.0f * cn1);
  }
}

// ---- epilogue kernel (r22 verified; grid 2048 -> rpw 4, full occupancy) ----
__global__ __launch_bounds__(256) void vq_epi(const float* __restrict__ z,
                                              const float* __restrict__ cb,
                                              const _Float16* __restrict__ lg,
                                              float* __restrict__ out,
                                              float* __restrict__ ws,
                                              int row_base, int nrows) {
  __shared__ float pacc[1024];
  __shared__ float redH[4];
  __shared__ float redS[4];
  const int tid = threadIdx.x;
  const int lane = tid & 63;
  const int wv = tid >> 6;
  const int gw = blockIdx.x * 4 + wv;  // 0..8191
  pacc[tid] = 0.0f; pacc[tid + 256] = 0.0f;
  pacc[tid + 512] = 0.0f; pacc[tid + 768] = 0.0f;
  float pl[16];
#pragma unroll
  for (int i = 0; i < 16; ++i) pl[i] = 0.0f;
  float hacc = 0.0f, sqacc = 0.0f;
  const int rpw = nrows >> 13;  // rows per wave (8192 waves)

#pragma unroll 1
  for (int rr = 0; rr < rpw; ++rr) {
    const int lri = gw * rpw + rr;      // chunk-local row
    const int row = row_base + lri;
    const _Float16* lr = lg + (size_t)lri * 1024;
    f16x4 a0 = *(const f16x4*)(lr + (lane << 2));
    f16x4 a1 = *(const f16x4*)(lr + 256 + (lane << 2));
    f16x4 a2 = *(const f16x4*)(lr + 512 + (lane << 2));
    f16x4 a3 = *(const f16x4*)(lr + 768 + (lane << 2));
    float vv[16];
    vv[0] = (float)a0[0]; vv[1] = (float)a0[1]; vv[2] = (float)a0[2]; vv[3] = (float)a0[3];
    vv[4] = (float)a1[0]; vv[5] = (float)a1[1]; vv[6] = (float)a1[2]; vv[7] = (float)a1[3];
    vv[8] = (float)a2[0]; vv[9] = (float)a2[1]; vv[10] = (float)a2[2]; vv[11] = (float)a2[3];
    vv[12] = (float)a3[0]; vv[13] = (float)a3[1]; vv[14] = (float)a3[2]; vv[15] = (float)a3[3];
    float m1 = -3.4e38f, m2v = -3.4e38f;
    int c1 = 0;
#pragma unroll
    for (int i = 0; i < 16; ++i) {
      float val = vv[i];
      int col = ((i >> 2) << 8) + (lane << 2) + (i & 3);
      if (val > m1) { m2v = m1; m1 = val; c1 = col; }
      else if (val > m2v) { m2v = val; }
    }
#pragma unroll
    for (int mk = 1; mk < 64; mk <<= 1) {
      float om1 = __shfl_xor(m1, mk, 64);
      int oc1 = __shfl_xor(c1, mk, 64);
      float om2 = __shfl_xor(m2v, mk, 64);
      if (om1 > m1 || (om1 == m1 && oc1 < c1)) { m2v = fmaxf(m1, om2); m1 = om1; c1 = oc1; }
      else { m2v = fmaxf(om1, m2v); }
    }
    const float rowmax = m1;
    const int bcol = c1;
    const bool danger = (m1 - m2v) < danger_thr(m1);
    float S = 0.f, T = 0.f;
#pragma unroll
    for (int i = 0; i < 16; ++i) {
      float e = __expf(vv[i] - rowmax);
      S += e;
      T = fmaf(e, vv[i], T);
      vv[i] = e;
    }
#pragma unroll
    for (int mk = 1; mk < 64; mk <<= 1) {
      S += __shfl_xor(S, mk, 64);
      T += __shfl_xor(T, mk, 64);
    }
    const float invZ = 1.0f / S;
    const float H = rowmax + logf(S) - T * invZ;
#pragma unroll
    for (int i = 0; i < 16; ++i) pl[i] = fmaf(vv[i], invZ, pl[i]);
    const float* zr = z + ((size_t)row << 8) + (lane << 2);
    const float* cr = cb + ((size_t)bcol << 8) + (lane << 2);
    float* orow = out + ((size_t)row << 8) + (lane << 2);
    float4 zv = *(const float4*)zr;
    float4 cv = *(const float4*)cr;
    float4 qv;
    qv.x = zv.x + (cv.x - zv.x);
    qv.y = zv.y + (cv.y - zv.y);
    qv.z = zv.z + (cv.z - zv.z);
    qv.w = zv.w + (cv.w - zv.w);
    *(float4*)orow = qv;
    float sq = 0.f;
    float dx = cv.x - zv.x; sq = fmaf(dx, dx, sq);
    dx = cv.y - zv.y; sq = fmaf(dx, dx, sq);
    dx = cv.z - zv.z; sq = fmaf(dx, dx, sq);
    dx = cv.w - zv.w; sq = fmaf(dx, dx, sq);
#pragma unroll
    for (int mk = 1; mk < 64; mk <<= 1) sq += __shfl_xor(sq, mk, 64);
    if (lane == 0) {
      hacc += H;
      sqacc += sq;
      if (danger) {
        out[OFF_IDX + row] = -(float)(bcol + 1);
        int p = atomicAdd((int*)ws + WL_CNT, 1);
        if (p < WL2_CAP) ((int*)ws)[WL2_BASE_F + p] = row;
      } else {
        out[OFF_IDX + row] = (float)bcol;
      }
    }
  }

  __syncthreads();  // pacc zeros visible to all waves
#pragma unroll
  for (int i = 0; i < 16; ++i)
    atomicAdd(&pacc[((i >> 2) << 8) + (lane << 2) + (i & 3)], pl[i]);
  if (lane == 0) { redH[wv] = hacc; redS[wv] = sqacc; }
  __syncthreads();
  atomicAdd(&ws[tid], pacc[tid]);
  atomicAdd(&ws[tid + 256], pacc[tid + 256]);
  atomicAdd(&ws[tid + 512], pacc[tid + 512]);
  atomicAdd(&ws[tid + 768], pacc[tid + 768]);
  if (tid == 0) {
    atomicAdd(&ws[1024], (redH[0] + redH[1]) + (redH[2] + redH[3]));
    atomicAdd(&ws[1025], (redS[0] + redS[1]) + (redS[2] + redS[3]));
  }
}

// ---- contested-row fixer v4 (r22 verified, unchanged) ----
__global__ __launch_bounds__(256) void vq_fix2(const float* __restrict__ z,
                                               const float* __restrict__ cb,
                                               const _Float16* __restrict__ lg,
                                               float* __restrict__ out,
                                               const float* __restrict__ ws) {
  __shared__ int candk[4][64];
  __shared__ int candn[4];
  const int tid = threadIdx.x;
  const int wv = tid >> 6, lane = tid & 63;
  const float* cnorm = ws + 1026;
  int cnt = ((const int*)ws)[WL_CNT];
  if (cnt > WL2_CAP) cnt = WL2_CAP;
  const int gwave = blockIdx.x * 4 + wv;
  const int nw = gridDim.x * 4;

#pragma unroll 1
  for (int i = gwave; i < cnt; i += nw) {
    const int row = ((const int*)ws)[WL2_BASE_F + i];
    const float* zr = z + ((size_t)row << 8);
    const _Float16* lr = lg + ((size_t)row << 10);

    f16x4 a0 = *(const f16x4*)(lr + (lane << 2));
    f16x4 a1 = *(const f16x4*)(lr + 256 + (lane << 2));
    f16x4 a2 = *(const f16x4*)(lr + 512 + (lane << 2));
    f16x4 a3 = *(const f16x4*)(lr + 768 + (lane << 2));
    float vv[16];
    vv[0] = (float)a0[0]; vv[1] = (float)a0[1]; vv[2] = (float)a0[2]; vv[3] = (float)a0[3];
    vv[4] = (float)a1[0]; vv[5] = (float)a1[1]; vv[6] = (float)a1[2]; vv[7] = (float)a1[3];
    vv[8] = (float)a2[0]; vv[9] = (float)a2[1]; vv[10] = (float)a2[2]; vv[11] = (float)a2[3];
    vv[12] = (float)a3[0]; vv[13] = (float)a3[1]; vv[14] = (float)a3[2]; vv[15] = (float)a3[3];
    float m1 = vv[0];
#pragma unroll
    for (int t = 1; t < 16; ++t) m1 = fmaxf(m1, vv[t]);
#pragma unroll
    for (int mk = 1; mk < 64; mk <<= 1) m1 = fmaxf(m1, __shfl_xor(m1, mk, 64));
    const float cthr = danger_thr(m1);

    if (lane == 0) candn[wv] = 0;
    __threadfence_block();
#pragma unroll
    for (int t = 0; t < 16; ++t) {
      if (vv[t] >= m1 - cthr) {
        int k = ((t >> 2) << 8) + (lane << 2) + (t & 3);
        int p = atomicAdd(&candn[wv], 1);
        if (p < 64) candk[wv][p] = k;
      }
    }
    __threadfence_block();
    const int nc = candn[wv];
    if (nc > 64) continue;  // wave-uniform; row stays flagged for after-sweep

    float r;
    {
      int h = (lane & 15) >> 3, j = lane & 7;
      const float* xp = zr + h * 128 + j;
      float x = xp[0];
      float sq = x * x; NOFUSE(sq);
      r = sq;
#pragma unroll
      for (int tt = 1; tt < 16; ++tt) {
        x = xp[8 * tt];
        sq = x * x; NOFUSE(sq);
        r = r + sq;
      }
    }
    r = r + __shfl_xor(r, 1, 64);
    r = r + __shfl_xor(r, 2, 64);
    r = r + __shfl_xor(r, 4, 64);
    r = r + __shfl_xor(r, 8, 64);
    const float znorm = __shfl(r, 0, 64);

    float bd = 3.4e38f;
    int bk = 0x7FFFFFFF;
    if (lane < nc) {
      int k = candk[wv][lane];
      const float* cr = cb + ((size_t)k << 8);
      float acc = 0.0f;
#pragma unroll 8
      for (int d = 0; d < 256; ++d) acc = fmaf(zr[d], cr[d], acc);
      bd = (znorm - 2.0f * acc) + cnorm[k];
      bk = k;
    }
#pragma unroll
    for (int mk = 1; mk < 64; mk <<= 1) {
      float od = __shfl_xor(bd, mk, 64);
      int ok = __shfl_xor(bk, mk, 64);
      if (od < bd || (od == bd && ok < bk)) { bd = od; bk = ok; }
    }
    const int bkf = bk;

    float iv = out[OFF_IDX + row];
    int kold = (iv < 0.0f) ? ((int)(-iv) - 1) : (int)iv;
    if (bkf != kold) {
#pragma unroll
      for (int q = 0; q < 4; ++q) {
        int d0 = lane + q * 64;
        float zd = zr[d0], cd = cb[((size_t)bkf << 8) + d0];
        out[((size_t)row << 8) + d0] = zd + (cd - zd);
      }
    }
    if (lane == 0) out[OFF_IDX + row] = (float)bkf;
  }
}

// ---- after-sweep + final loss (r10 verified; normally finds zero flags) ----
__global__ __launch_bounds__(256) void vq_fixfinal(const float* __restrict__ z,
                                                   const float* __restrict__ cb,
                                                   float* __restrict__ out,
                                                   const float* __restrict__ ws) {
  if (blockIdx.x == 256) {
    __shared__ float red[256];
    int t = threadIdx.x;
    float s = 0.f;
#pragma unroll
    for (int i = 0; i < 4; ++i) {
      float a = ws[t + i * 256] * (1.0f / 32768.0f);
      s += a * logf(a + 1e-5f);
    }
    red[t] = s;
    __syncthreads();
    for (int st = 128; st > 0; st >>= 1) {
      if (t < st) red[t] += red[t + st];
      __syncthreads();
    }
    if (t == 0) {
      float avg_entropy = -red[0];
      float sample_entropy = ws[1024] * (1.0f / 32768.0f);
      float m = ws[1025] * (1.0f / 8388608.0f);
      out[OFF_COMMIT] = 0.25f * m;
      out[OFF_EMBED] = m;
      out[OFF_ENT] = 0.1f * (sample_entropy - avg_entropy);
    }
    return;
  }

  const int lane = threadIdx.x & 63;
  const int gwave = (int)((blockIdx.x * 256 + threadIdx.x) >> 6);  // 0..1023
  const int rbase = gwave * 32;
  const float* cnorm = ws + 1026;

  float iv = (lane < 32) ? out[OFF_IDX + rbase + lane] : 0.0f;
  unsigned long long mask = __ballot(iv < 0.0f);
  while (mask) {
    int bit = __ffsll((long long)mask) - 1;
    mask &= mask - 1;
    int row = rbase + bit;
    float ivr = __shfl(iv, bit, 64);
    int kold = (int)(-ivr) - 1;
    const float* zr = z + (size_t)row * DDIM;

    float r;
    {
      int h = (lane & 15) >> 3, j = lane & 7;
      const float* xp = zr + h * 128 + j;
      float x = xp[0];
      float sq = x * x; NOFUSE(sq);
      r = sq;
#pragma unroll
      for (int tt = 1; tt < 16; ++tt) {
        x = xp[8 * tt];
        sq = x * x; NOFUSE(sq);
        r = r + sq;
      }
    }
    r = r + __shfl_xor(r, 1, 64);
    r = r + __shfl_xor(r, 2, 64);
    r = r + __shfl_xor(r, 4, 64);
    r = r + __shfl_xor(r, 8, 64);
    const float znorm = __shfl(r, 0, 64);

    float bd = 3.4e38f;
    int bk = 0;
#pragma unroll 1
    for (int t = 0; t < 16; ++t) {
      int k = lane + t * 64;
      const float* cr = cb + (size_t)k * DDIM;
      float acc = 0.0f;
#pragma unroll 8
      for (int d = 0; d < 256; ++d) acc = fmaf(zr[d], cr[d], acc);
      float dist = (znorm - 2.0f * acc) + cnorm[k];
      if (dist < bd) { bd = dist; bk = k; }
    }
#pragma unroll
    for (int m = 1; m < 64; m <<= 1) {
      float od = __shfl_xor(bd, m, 64);
      int ok = __shfl_xor(bk, m, 64);
      if (od < bd || (od == bd && ok < bk)) { bd = od; bk = ok; }
    }

    if (bk != kold) {
      const float* cr = cb + (size_t)bk * DDIM;
#pragma unroll
      for (int i = 0; i < 4; ++i) {
        int d0 = lane + i * 64;
        float zd = zr[d0], cd = cr[d0];
        out[(size_t)row * DDIM + d0] = zd + (cd - zd);
      }
    }
    if (lane == 0) out[OFF_IDX + row] = (float)bk;
  }
}

// ---- MFMA main v5 (r10 verified) — fallback if ws too small for logits ----
__global__ __launch_bounds__(1024, 4) void vq_main5(const float* __restrict__ z,
                                                    const float* __restrict__ cb,
                                                    const unsigned short* __restrict__ img,
                                                    float* __restrict__ out,
                                                    float* __restrict__ ws) {
  __shared__ __align__(16) unsigned char smem[102656];
  float* pacc = (float*)smem;
  unsigned short* zh_s = (unsigned short*)(smem + 4096);
  unsigned short* zl_s = (unsigned short*)(smem + 20480);
  float* logits = (float*)(smem + 36864);
  float* redH = (float*)(smem + 102400);
  float* redS = (float*)(smem + 102464);

  const int tid = threadIdx.x;
  const int w = tid >> 6;
  const int lane = tid & 63;
  const int l31 = lane & 31, lhi = lane >> 5;
  const float* cnorm = ws + 1026;
  const int ct0 = w * 2, ct1 = w * 2 + 1;
  const unsigned short* pw = img + lane * 8;
  const float cn0 = cnorm[ct0 * 32 + l31];
  const float cn1 = cnorm[ct1 * 32 + l31];
  const int erow = tid >> 6, ecl = tid & 63;

  pacc[tid] = 0.0f;
  float hacc = 0.0f, sqacc = 0.0f;

#pragma unroll 1
  for (int t = 0; t < 4; ++t) {
    const int nbase = (blockIdx.x * 4 + t) * 32;
#pragma unroll
    for (int i = 0; i < 8; ++i) {
      int idx = tid + (i << 10);
      int row = idx >> 8, k = idx & 255;
      float x = z[((size_t)(nbase + row) << 8) + k];
      unsigned short hh, ll;
      bf16split(x, hh, ll);
      int uoff = (row << 8) | ((((k >> 3) ^ row) & 31) << 3) | (k & 7);
      zh_s[uoff] = hh; zl_s[uoff] = ll;
    }
    __syncthreads();

    f32x16 acc0, acc1;
#pragma unroll
    for (int e = 0; e < 16; ++e) { acc0[e] = 0.0f; acc1[e] = 0.0f; }

    const unsigned short* p0 = pw + ct0 * 1024;
    const unsigned short* p1 = pw + ct1 * 1024;
    bf16x8 nbh0 = *(const bf16x8*)(p0);
    bf16x8 nbl0 = *(const bf16x8*)(p0 + 512);
    bf16x8 nbh1 = *(const bf16x8*)(p1);
    bf16x8 nbl1 = *(const bf16x8*)(p1 + 512);
    int au0 = (l31 << 8) | (((lhi ^ l31) & 31) << 3);
    bf16x8 nazh = *(const bf16x8*)(zh_s + au0);
    bf16x8 nazl = *(const bf16x8*)(zl_s + au0);

#pragma unroll 1
    for (int kc = 0; kc < 16; ++kc) {
      bf16x8 ch0 = nbh0, cl0 = nbl0, ch1 = nbh1, cl1 = nbl1;
      bf16x8 cah = nazh, cal = nazl;
      const int kn = (kc + 1) & 15;
      const unsigned short* pk = pw + kn * 32768;
      const unsigned short* q0 = pk + ct0 * 1024;
      const unsigned short* q1 = pk + ct1 * 1024;
      nbh0 = *(const bf16x8*)(q0);
      nbl0 = *(const bf16x8*)(q0 + 512);
      nbh1 = *(const bf16x8*)(q1);
      nbl1 = *(const bf16x8*)(q1 + 512);
      const int aun = (l31 << 8) | (((((kn << 1) | lhi) ^ l31) & 31) << 3);
      nazh = *(const bf16x8*)(zh_s + aun);
      nazl = *(const bf16x8*)(zl_s + aun);
      acc0 = MFMA32(cah, ch0, acc0);
      acc1 = MFMA32(cah, ch1, acc1);
      acc0 = MFMA32(cah, cl0, acc0);
      acc1 = MFMA32(cah, cl1, acc1);
      acc0 = MFMA32(cal, ch0, acc0);
      acc1 = MFMA32(cal, ch1, acc1);
    }

#pragma unroll
    for (int g = 0; g < 2; ++g) {
      __syncthreads();
#pragma unroll
      for (int q = 0; q < 8; ++q) {
        int reg = q + (g << 3);
        int r16 = (q & 3) | ((q >> 2) << 3) | (lhi << 2);
        logits[(r16 << 10) + ct0 * 32 + l31] = 200.0f * acc0[reg] - 100.0f * cn0;
        logits[(r16 << 10) + ct1 * 32 + l31] = 200.0f * acc1[reg] - 100.0f * cn1;
      }
      __syncthreads();
      const int grow = nbase + (g << 4) + erow;
      float v2[16];
#pragma unroll
      for (int m = 0; m < 16; ++m) v2[m] = logits[(erow << 10) + ecl + (m << 6)];
      float m1 = -3.4e38f, m2v = -3.4e38f;
      int c1 = 0;
#pragma unroll
      for (int m = 0; m < 16; ++m) {
        float val = v2[m];
        if (val > m1) { m2v = m1; m1 = val; c1 = ecl + (m << 6); }
        else if (val > m2v) { m2v = val; }
      }
#pragma unroll
      for (int mk = 1; mk < 64; mk <<= 1) {
        float om1 = __shfl_xor(m1, mk, 64);
        int oc1 = __shfl_xor(c1, mk, 64);
        float om2 = __shfl_xor(m2v, mk, 64);
        if (om1 > m1 || (om1 == m1 && oc1 < c1)) { m2v = fmaxf(m1, om2); m1 = om1; c1 = oc1; }
        else { m2v = fmaxf(om1, m2v); }
      }
      const float rowmax = m1;
      const int bcol = c1;
      const bool danger = (m1 - m2v) < 0.25f;
      float S = 0.f, T = 0.f;
#pragma unroll
      for (int m = 0; m < 16; ++m) {
        float e = __expf(v2[m] - rowmax);
        S += e;
        T = fmaf(e, v2[m], T);
        v2[m] = e;
      }
#pragma unroll
      for (int mk = 1; mk < 64; mk <<= 1) {
        S += __shfl_xor(S, mk, 64);
        T += __shfl_xor(T, mk, 64);
      }
      const float invZ = 1.0f / S;
      const float H = rowmax + logf(S) - T * invZ;
#pragma unroll
      for (int m = 0; m < 16; ++m) atomicAdd(&pacc[ecl + (m << 6)], v2[m] * invZ);
      float sq = 0.f;
      {
        const float* zr = z + ((size_t)grow << 8) + (ecl << 2);
        const float* cr = cb + ((size_t)bcol << 8) + (ecl << 2);
        float* orow = out + ((size_t)grow << 8) + (ecl << 2);
        float4 zv = *(const float4*)(zr);
        float4 cv = *(const float4*)(cr);
        float4 qv;
        qv.x = zv.x + (cv.x - zv.x);
        qv.y = zv.y + (cv.y - zv.y);
        qv.z = zv.z + (cv.z - zv.z);
        qv.w = zv.w + (cv.w - zv.w);
        *(float4*)(orow) = qv;
        float dx = cv.x - zv.x; sq = fmaf(dx, dx, sq);
        dx = cv.y - zv.y; sq = fmaf(dx, dx, sq);
        dx = cv.z - zv.z; sq = fmaf(dx, dx, sq);
        dx = cv.w - zv.w; sq = fmaf(dx, dx, sq);
      }
#pragma unroll
      for (int mk = 1; mk < 64; mk <<= 1) sq += __shfl_xor(sq, mk, 64);
      if (ecl == 0) {
        hacc += H;
        sqacc += sq;
        out[OFF_IDX + grow] = danger ? -(float)(bcol + 1) : (float)bcol;
      }
    }
  }

  if (ecl == 0) { redH[erow] = hacc; redS[erow] = sqacc; }
  __syncthreads();
  atomicAdd(&ws[tid], pacc[tid]);
  if (tid == 0) {
    float hs = 0.f, ss = 0.f;
#pragma unroll
    for (int i = 0; i < 16; ++i) { hs += redH[i]; ss += redS[i]; }
    atomicAdd(&ws[1024], hs);
    atomicAdd(&ws[1025], ss);
  }
}

extern "C" void kernel_launch(void* const* d_in, const int* in_sizes, int n_in,
                              void* d_out, int out_size, void* d_ws, size_t ws_size,
                              hipStream_t stream) {
  const float* z = (const float*)d_in[0];
  const float* cb = (const float*)d_in[1];
  float* out = (float*)d_out;
  float* ws = (float*)d_ws;
  const unsigned short* img = (const unsigned short*)(ws + WS_IMG_F);

  vq_pre<<<192, 256, 0, stream>>>(cb, ws);

  size_t need = ((size_t)WL2_BASE_F + WL2_CAP + 64) * 4ull;
  if (ws_size >= need) {
    _Float16* lgbuf = (_Float16*)(ws + WS_LG_F);
    vq_gemm64<<<NROWS / 64, 1024, 0, stream>>>(z, img, lgbuf, ws, 0);
    vq_epi<<<2048, 256, 0, stream>>>(z, cb, lgbuf, out, ws, 0, NROWS);
    vq_fix2<<<256, 256, 0, stream>>>(z, cb, lgbuf, out, ws);
  } else {
    vq_main5<<<256, 1024, 0, stream>>>(z, cb, img, out, ws);
  }
  vq_fixfinal<<<257, 256, 0, stream>>>(z, cb, out, ws);
}

// Round 25
// 129.189 us; speedup vs baseline: 1.1909x; 1.1909x over previous
//
#include <hip/hip_runtime.h>
#include <math.h>

#define NROWS 32768
#define DDIM 256
#define KEMB 1024

#define OFF_COMMIT 8388608
#define OFF_EMBED  8388609
#define OFF_ENT    8388610
#define OFF_IDX    8388611

// ws float layout: [0..1023] avg_prob sums, [1024] H sum, [1025] sqdiff sum,
// [1026..2049] cnorm, int[2052] worklist counter,
// [4096..266239] cb bf16 hi/lo fragment image (1 MB),
// [266240..) fp16 logits buffer (64 MB), int[WL2_BASE_F..] worklist.
#define WS_IMG_F 4096
#define WS_LG_F  266240
#define WL_CNT   2052
#define WL2_BASE_F (WS_LG_F + 16777216)
#define WL2_CAP  32768

// Magnitude-aware danger/candidate threshold (r22 verified):
//  |m1| < 2040  -> 1.25 ;  |m1| >= 2040 -> 2.5 (fp16 ulp=2 regime).
__device__ inline float danger_thr(float m1) {
  return (fabsf(m1) >= 2040.0f) ? 2.5f : 1.25f;
}

// prevent -ffp-contract=fast from fusing this mul into a following add
#define NOFUSE(x) asm volatile("" : "+v"(x))

typedef __attribute__((ext_vector_type(8))) short bf16x8;
typedef __attribute__((ext_vector_type(16))) float f32x16;
typedef __attribute__((ext_vector_type(4))) _Float16 f16x4;
#define MFMA32(a, b, c) __builtin_amdgcn_mfma_f32_32x32x16_bf16((a), (b), (c), 0, 0, 0)

// round-to-nearest-even fp32 -> bf16 hi + bf16 lo split
__device__ inline void bf16split(float x, unsigned short& h, unsigned short& l) {
  unsigned u = __float_as_uint(x);
  unsigned r = u + 0x7FFFu + ((u >> 16) & 1u);
  h = (unsigned short)(r >> 16);
  float hf = __uint_as_float(r & 0xFFFF0000u);
  float lo = x - hf;  // exact (Sterbenz)
  unsigned ul = __float_as_uint(lo);
  unsigned rl = ul + 0x7FFFu + ((ul >> 16) & 1u);
  l = (unsigned short)(rl >> 16);
}

// ---- fused pre-pass (r10 verified; + worklist counter zero) ----
__global__ __launch_bounds__(256) void vq_pre(const float* __restrict__ cb,
                                              float* __restrict__ ws) {
  const int tid = threadIdx.x;
  if (blockIdx.x == 0 && tid == 0) ((int*)ws)[WL_CNT] = 0;
  if (blockIdx.x < 64) {
    int t = blockIdx.x * 256 + tid;  // [0,16384)
    if (t < 1026) ws[t] = 0.0f;
    int row = t >> 4;  // 0..1023
    int l = t & 15;
    int h = l >> 3, j = l & 7;
    const float* xp = cb + (size_t)row * DDIM + h * 128 + j;
    float x = xp[0];
    float sq = x * x; NOFUSE(sq);
    float r = sq;
#pragma unroll
    for (int tt = 1; tt < 16; ++tt) {
      x = xp[8 * tt];
      sq = x * x; NOFUSE(sq);
      r = r + sq;
    }
    r = r + __shfl_xor(r, 1, 64);
    r = r + __shfl_xor(r, 2, 64);
    r = r + __shfl_xor(r, 4, 64);
    r = r + __shfl_xor(r, 8, 64);
    if (l == 0) ws[1026 + row] = r;
  } else {
    unsigned short* img = (unsigned short*)(ws + WS_IMG_F);
    int t = (blockIdx.x - 64) * 256 + tid;  // [0,32768)
    int kc = t >> 11;
    int ct = (t >> 6) & 31;
    int lane = t & 63;
    int l31 = lane & 31, lhi = lane >> 5;
    const float* src = cb + ((size_t)(ct * 32 + l31) << 8) + kc * 16 + lhi * 8;
    float4 v0 = *(const float4*)(src);
    float4 v1 = *(const float4*)(src + 4);
    bf16x8 hv, lv;
    unsigned short hh, ll;
    bf16split(v0.x, hh, ll); hv[0] = hh; lv[0] = ll;
    bf16split(v0.y, hh, ll); hv[1] = hh; lv[1] = ll;
    bf16split(v0.z, hh, ll); hv[2] = hh; lv[2] = ll;
    bf16split(v0.w, hh, ll); hv[3] = hh; lv[3] = ll;
    bf16split(v1.x, hh, ll); hv[4] = hh; lv[4] = ll;
    bf16split(v1.y, hh, ll); hv[5] = hh; lv[5] = ll;
    bf16split(v1.z, hh, ll); hv[6] = hh; lv[6] = ll;
    bf16split(v1.w, hh, ll); hv[7] = hh; lv[7] = ll;
    size_t f = ((size_t)(kc * 32 + ct) * 2) * 64 + lane;  // hl=0
    *(bf16x8*)(img + f * 8) = hv;
    *(bf16x8*)(img + (f + 64) * 8) = lv;                  // hl=1
  }
}

// ---- GEMM kernel BM=64 (r23 verified, unchanged) ----
__global__ __launch_bounds__(1024, 4) void vq_gemm64(const float* __restrict__ z,
                                                     const unsigned short* __restrict__ img,
                                                     _Float16* __restrict__ lg,
                                                     const float* __restrict__ ws,
                                                     int row_base) {
  __shared__ __align__(16) unsigned char smem[65536];
  unsigned short* zh_s = (unsigned short*)smem;
  unsigned short* zl_s = (unsigned short*)(smem + 32768);
  const int tid = threadIdx.x;
  const int w = tid >> 6;
  const int lane = tid & 63;
  const int l31 = lane & 31, lhi = lane >> 5;
  const int ct0 = w * 2, ct1 = w * 2 + 1;
  const unsigned short* pw = img + lane * 8;
  const float* cnorm = ws + 1026;
  const int nbase = row_base + blockIdx.x * 64;

#pragma unroll
  for (int i = 0; i < 16; ++i) {
    int idx = tid + (i << 10);
    int row = idx >> 8, k = idx & 255;
    float x = z[((size_t)(nbase + row) << 8) + k];
    unsigned short hh, ll;
    bf16split(x, hh, ll);
    int uoff = (row << 8) | ((((k >> 3) ^ row) & 31) << 3) | (k & 7);
    zh_s[uoff] = hh; zl_s[uoff] = ll;
  }
  __syncthreads();

  f32x16 acc00, acc01, acc10, acc11;
#pragma unroll
  for (int e = 0; e < 16; ++e) {
    acc00[e] = 0.0f; acc01[e] = 0.0f; acc10[e] = 0.0f; acc11[e] = 0.0f;
  }

  const unsigned short* p0 = pw + ct0 * 1024;
  const unsigned short* p1 = pw + ct1 * 1024;
  bf16x8 nbh0 = *(const bf16x8*)(p0);
  bf16x8 nbl0 = *(const bf16x8*)(p0 + 512);
  bf16x8 nbh1 = *(const bf16x8*)(p1);
  bf16x8 nbl1 = *(const bf16x8*)(p1 + 512);

#pragma unroll 1
  for (int kc = 0; kc < 16; ++kc) {
    bf16x8 ch0 = nbh0, cl0 = nbl0, ch1 = nbh1, cl1 = nbl1;
    const int kn = (kc + 1) & 15;
    const unsigned short* pk = pw + kn * 32768;
    const unsigned short* q0 = pk + ct0 * 1024;
    const unsigned short* q1 = pk + ct1 * 1024;
    nbh0 = *(const bf16x8*)(q0);
    nbl0 = *(const bf16x8*)(q0 + 512);
    nbh1 = *(const bf16x8*)(q1);
    nbl1 = *(const bf16x8*)(q1 + 512);
    const int au0 = (l31 << 8) | (((((kc << 1) | lhi) ^ l31) & 31) << 3);
    const int au1 = ((32 + l31) << 8) | (((((kc << 1) | lhi) ^ l31) & 31) << 3);
    bf16x8 azh0 = *(const bf16x8*)(zh_s + au0);
    bf16x8 azl0 = *(const bf16x8*)(zl_s + au0);
    bf16x8 azh1 = *(const bf16x8*)(zh_s + au1);
    bf16x8 azl1 = *(const bf16x8*)(zl_s + au1);
    acc00 = MFMA32(azh0, ch0, acc00);
    acc01 = MFMA32(azh0, ch1, acc01);
    acc10 = MFMA32(azh1, ch0, acc10);
    acc11 = MFMA32(azh1, ch1, acc11);
    acc00 = MFMA32(azh0, cl0, acc00);
    acc01 = MFMA32(azh0, cl1, acc01);
    acc10 = MFMA32(azh1, cl0, acc10);
    acc11 = MFMA32(azh1, cl1, acc11);
    acc00 = MFMA32(azl0, ch0, acc00);
    acc01 = MFMA32(azl0, ch1, acc01);
    acc10 = MFMA32(azl1, ch0, acc10);
    acc11 = MFMA32(azl1, ch1, acc11);
  }

  const float cn0 = cnorm[ct0 * 32 + l31];
  const float cn1 = cnorm[ct1 * 32 + l31];
  _Float16* lrow0 = lg + (size_t)(blockIdx.x * 64) * 1024;
  _Float16* lrow1 = lrow0 + (size_t)32 * 1024;
#pragma unroll
  for (int reg = 0; reg < 16; ++reg) {
    int ro = (reg & 3) + 8 * ((reg >> 2) & 1) + 16 * (reg >> 3) + 4 * lhi;
    lrow0[(size_t)ro * 1024 + ct0 * 32 + l31] =
        (_Float16)(200.0f * acc00[reg] - 100.0f * cn0);
    lrow0[(size_t)ro * 1024 + ct1 * 32 + l31] =
        (_Float16)(200.0f * acc01[reg] - 100.0f * cn1);
    lrow1[(size_t)ro * 1024 + ct0 * 32 + l31] =
        (_Float16)(200.0f * acc10[reg] - 100.0f * cn0);
    lrow1[(size_t)ro * 1024 + ct1 * 32 + l31] =
        (_Float16)(200.0f * acc11[reg] - 100.0f * cn1);
  }
}

// ---- epilogue kernel (r23 verified; 1024 blocks, rpw 8) ----
__global__ __launch_bounds__(256) void vq_epi(const float* __restrict__ z,
                                              const float* __restrict__ cb,
                                              const _Float16* __restrict__ lg,
                                              float* __restrict__ out,
                                              float* __restrict__ ws,
                                              int row_base, int nrows) {
  __shared__ float pacc[1024];
  __shared__ float redH[4];
  __shared__ float redS[4];
  const int tid = threadIdx.x;
  const int lane = tid & 63;
  const int wv = tid >> 6;
  const int gw = blockIdx.x * 4 + wv;  // 0..4095
  pacc[tid] = 0.0f; pacc[tid + 256] = 0.0f;
  pacc[tid + 512] = 0.0f; pacc[tid + 768] = 0.0f;
  float pl[16];
#pragma unroll
  for (int i = 0; i < 16; ++i) pl[i] = 0.0f;
  float hacc = 0.0f, sqacc = 0.0f;
  const int rpw = nrows >> 12;  // rows per wave (4096 waves)

#pragma unroll 1
  for (int rr = 0; rr < rpw; ++rr) {
    const int lri = gw * rpw + rr;      // chunk-local row
    const int row = row_base + lri;
    const _Float16* lr = lg + (size_t)lri * 1024;
    f16x4 a0 = *(const f16x4*)(lr + (lane << 2));
    f16x4 a1 = *(const f16x4*)(lr + 256 + (lane << 2));
    f16x4 a2 = *(const f16x4*)(lr + 512 + (lane << 2));
    f16x4 a3 = *(const f16x4*)(lr + 768 + (lane << 2));
    float vv[16];
    vv[0] = (float)a0[0]; vv[1] = (float)a0[1]; vv[2] = (float)a0[2]; vv[3] = (float)a0[3];
    vv[4] = (float)a1[0]; vv[5] = (float)a1[1]; vv[6] = (float)a1[2]; vv[7] = (float)a1[3];
    vv[8] = (float)a2[0]; vv[9] = (float)a2[1]; vv[10] = (float)a2[2]; vv[11] = (float)a2[3];
    vv[12] = (float)a3[0]; vv[13] = (float)a3[1]; vv[14] = (float)a3[2]; vv[15] = (float)a3[3];
    float m1 = -3.4e38f, m2v = -3.4e38f;
    int c1 = 0;
#pragma unroll
    for (int i = 0; i < 16; ++i) {
      float val = vv[i];
      int col = ((i >> 2) << 8) + (lane << 2) + (i & 3);
      if (val > m1) { m2v = m1; m1 = val; c1 = col; }
      else if (val > m2v) { m2v = val; }
    }
#pragma unroll
    for (int mk = 1; mk < 64; mk <<= 1) {
      float om1 = __shfl_xor(m1, mk, 64);
      int oc1 = __shfl_xor(c1, mk, 64);
      float om2 = __shfl_xor(m2v, mk, 64);
      if (om1 > m1 || (om1 == m1 && oc1 < c1)) { m2v = fmaxf(m1, om2); m1 = om1; c1 = oc1; }
      else { m2v = fmaxf(om1, m2v); }
    }
    const float rowmax = m1;
    const int bcol = c1;
    const bool danger = (m1 - m2v) < danger_thr(m1);
    float S = 0.f, T = 0.f;
#pragma unroll
    for (int i = 0; i < 16; ++i) {
      float e = __expf(vv[i] - rowmax);
      S += e;
      T = fmaf(e, vv[i], T);
      vv[i] = e;
    }
#pragma unroll
    for (int mk = 1; mk < 64; mk <<= 1) {
      S += __shfl_xor(S, mk, 64);
      T += __shfl_xor(T, mk, 64);
    }
    const float invZ = 1.0f / S;
    const float H = rowmax + logf(S) - T * invZ;
#pragma unroll
    for (int i = 0; i < 16; ++i) pl[i] = fmaf(vv[i], invZ, pl[i]);
    const float* zr = z + ((size_t)row << 8) + (lane << 2);
    const float* cr = cb + ((size_t)bcol << 8) + (lane << 2);
    float* orow = out + ((size_t)row << 8) + (lane << 2);
    float4 zv = *(const float4*)zr;
    float4 cv = *(const float4*)cr;
    float4 qv;
    qv.x = zv.x + (cv.x - zv.x);
    qv.y = zv.y + (cv.y - zv.y);
    qv.z = zv.z + (cv.z - zv.z);
    qv.w = zv.w + (cv.w - zv.w);
    *(float4*)orow = qv;
    float sq = 0.f;
    float dx = cv.x - zv.x; sq = fmaf(dx, dx, sq);
    dx = cv.y - zv.y; sq = fmaf(dx, dx, sq);
    dx = cv.z - zv.z; sq = fmaf(dx, dx, sq);
    dx = cv.w - zv.w; sq = fmaf(dx, dx, sq);
#pragma unroll
    for (int mk = 1; mk < 64; mk <<= 1) sq += __shfl_xor(sq, mk, 64);
    if (lane == 0) {
      hacc += H;
      sqacc += sq;
      if (danger) {
        out[OFF_IDX + row] = -(float)(bcol + 1);
        int p = atomicAdd((int*)ws + WL_CNT, 1);
        if (p < WL2_CAP) ((int*)ws)[WL2_BASE_F + p] = row;
      } else {
        out[OFF_IDX + row] = (float)bcol;
      }
    }
  }

  __syncthreads();  // pacc zeros visible to all waves
#pragma unroll
  for (int i = 0; i < 16; ++i)
    atomicAdd(&pacc[((i >> 2) << 8) + (lane << 2) + (i & 3)], pl[i]);
  if (lane == 0) { redH[wv] = hacc; redS[wv] = sqacc; }
  __syncthreads();
  atomicAdd(&ws[tid], pacc[tid]);
  atomicAdd(&ws[tid + 256], pacc[tid + 256]);
  atomicAdd(&ws[tid + 512], pacc[tid + 512]);
  atomicAdd(&ws[tid + 768], pacc[tid + 768]);
  if (tid == 0) {
    atomicAdd(&ws[1024], (redH[0] + redH[1]) + (redH[2] + redH[3]));
    atomicAdd(&ws[1025], (redS[0] + redS[1]) + (redS[2] + redS[3]));
  }
}

// ---- contested-row fixer v4 (r22 verified, unchanged) ----
__global__ __launch_bounds__(256) void vq_fix2(const float* __restrict__ z,
                                               const float* __restrict__ cb,
                                               const _Float16* __restrict__ lg,
                                               float* __restrict__ out,
                                               const float* __restrict__ ws) {
  __shared__ int candk[4][64];
  __shared__ int candn[4];
  const int tid = threadIdx.x;
  const int wv = tid >> 6, lane = tid & 63;
  const float* cnorm = ws + 1026;
  int cnt = ((const int*)ws)[WL_CNT];
  if (cnt > WL2_CAP) cnt = WL2_CAP;
  const int gwave = blockIdx.x * 4 + wv;
  const int nw = gridDim.x * 4;

#pragma unroll 1
  for (int i = gwave; i < cnt; i += nw) {
    const int row = ((const int*)ws)[WL2_BASE_F + i];
    const float* zr = z + ((size_t)row << 8);
    const _Float16* lr = lg + ((size_t)row << 10);

    f16x4 a0 = *(const f16x4*)(lr + (lane << 2));
    f16x4 a1 = *(const f16x4*)(lr + 256 + (lane << 2));
    f16x4 a2 = *(const f16x4*)(lr + 512 + (lane << 2));
    f16x4 a3 = *(const f16x4*)(lr + 768 + (lane << 2));
    float vv[16];
    vv[0] = (float)a0[0]; vv[1] = (float)a0[1]; vv[2] = (float)a0[2]; vv[3] = (float)a0[3];
    vv[4] = (float)a1[0]; vv[5] = (float)a1[1]; vv[6] = (float)a1[2]; vv[7] = (float)a1[3];
    vv[8] = (float)a2[0]; vv[9] = (float)a2[1]; vv[10] = (float)a2[2]; vv[11] = (float)a2[3];
    vv[12] = (float)a3[0]; vv[13] = (float)a3[1]; vv[14] = (float)a3[2]; vv[15] = (float)a3[3];
    float m1 = vv[0];
#pragma unroll
    for (int t = 1; t < 16; ++t) m1 = fmaxf(m1, vv[t]);
#pragma unroll
    for (int mk = 1; mk < 64; mk <<= 1) m1 = fmaxf(m1, __shfl_xor(m1, mk, 64));
    const float cthr = danger_thr(m1);

    if (lane == 0) candn[wv] = 0;
    __threadfence_block();
#pragma unroll
    for (int t = 0; t < 16; ++t) {
      if (vv[t] >= m1 - cthr) {
        int k = ((t >> 2) << 8) + (lane << 2) + (t & 3);
        int p = atomicAdd(&candn[wv], 1);
        if (p < 64) candk[wv][p] = k;
      }
    }
    __threadfence_block();
    const int nc = candn[wv];
    if (nc > 64) continue;  // wave-uniform; row stays flagged for after-sweep

    float r;
    {
      int h = (lane & 15) >> 3, j = lane & 7;
      const float* xp = zr + h * 128 + j;
      float x = xp[0];
      float sq = x * x; NOFUSE(sq);
      r = sq;
#pragma unroll
      for (int tt = 1; tt < 16; ++tt) {
        x = xp[8 * tt];
        sq = x * x; NOFUSE(sq);
        r = r + sq;
      }
    }
    r = r + __shfl_xor(r, 1, 64);
    r = r + __shfl_xor(r, 2, 64);
    r = r + __shfl_xor(r, 4, 64);
    r = r + __shfl_xor(r, 8, 64);
    const float znorm = __shfl(r, 0, 64);

    float bd = 3.4e38f;
    int bk = 0x7FFFFFFF;
    if (lane < nc) {
      int k = candk[wv][lane];
      const float* cr = cb + ((size_t)k << 8);
      float acc = 0.0f;
#pragma unroll 8
      for (int d = 0; d < 256; ++d) acc = fmaf(zr[d], cr[d], acc);
      bd = (znorm - 2.0f * acc) + cnorm[k];
      bk = k;
    }
#pragma unroll
    for (int mk = 1; mk < 64; mk <<= 1) {
      float od = __shfl_xor(bd, mk, 64);
      int ok = __shfl_xor(bk, mk, 64);
      if (od < bd || (od == bd && ok < bk)) { bd = od; bk = ok; }
    }
    const int bkf = bk;

    float iv = out[OFF_IDX + row];
    int kold = (iv < 0.0f) ? ((int)(-iv) - 1) : (int)iv;
    if (bkf != kold) {
#pragma unroll
      for (int q = 0; q < 4; ++q) {
        int d0 = lane + q * 64;
        float zd = zr[d0], cd = cb[((size_t)bkf << 8) + d0];
        out[((size_t)row << 8) + d0] = zd + (cd - zd);
      }
    }
    if (lane == 0) out[OFF_IDX + row] = (float)bkf;
  }
}

// ---- after-sweep + final loss (r10 verified; normally finds zero flags) ----
__global__ __launch_bounds__(256) void vq_fixfinal(const float* __restrict__ z,
                                                   const float* __restrict__ cb,
                                                   float* __restrict__ out,
                                                   const float* __restrict__ ws) {
  if (blockIdx.x == 256) {
    __shared__ float red[256];
    int t = threadIdx.x;
    float s = 0.f;
#pragma unroll
    for (int i = 0; i < 4; ++i) {
      float a = ws[t + i * 256] * (1.0f / 32768.0f);
      s += a * logf(a + 1e-5f);
    }
    red[t] = s;
    __syncthreads();
    for (int st = 128; st > 0; st >>= 1) {
      if (t < st) red[t] += red[t + st];
      __syncthreads();
    }
    if (t == 0) {
      float avg_entropy = -red[0];
      float sample_entropy = ws[1024] * (1.0f / 32768.0f);
      float m = ws[1025] * (1.0f / 8388608.0f);
      out[OFF_COMMIT] = 0.25f * m;
      out[OFF_EMBED] = m;
      out[OFF_ENT] = 0.1f * (sample_entropy - avg_entropy);
    }
    return;
  }

  const int lane = threadIdx.x & 63;
  const int gwave = (int)((blockIdx.x * 256 + threadIdx.x) >> 6);  // 0..1023
  const int rbase = gwave * 32;
  const float* cnorm = ws + 1026;

  float iv = (lane < 32) ? out[OFF_IDX + rbase + lane] : 0.0f;
  unsigned long long mask = __ballot(iv < 0.0f);
  while (mask) {
    int bit = __ffsll((long long)mask) - 1;
    mask &= mask - 1;
    int row = rbase + bit;
    float ivr = __shfl(iv, bit, 64);
    int kold = (int)(-ivr) - 1;
    const float* zr = z + (size_t)row * DDIM;

    float r;
    {
      int h = (lane & 15) >> 3, j = lane & 7;
      const float* xp = zr + h * 128 + j;
      float x = xp[0];
      float sq = x * x; NOFUSE(sq);
      r = sq;
#pragma unroll
      for (int tt = 1; tt < 16; ++tt) {
        x = xp[8 * tt];
        sq = x * x; NOFUSE(sq);
        r = r + sq;
      }
    }
    r = r + __shfl_xor(r, 1, 64);
    r = r + __shfl_xor(r, 2, 64);
    r = r + __shfl_xor(r, 4, 64);
    r = r + __shfl_xor(r, 8, 64);
    const float znorm = __shfl(r, 0, 64);

    float bd = 3.4e38f;
    int bk = 0;
#pragma unroll 1
    for (int t = 0; t < 16; ++t) {
      int k = lane + t * 64;
      const float* cr = cb + (size_t)k * DDIM;
      float acc = 0.0f;
#pragma unroll 8
      for (int d = 0; d < 256; ++d) acc = fmaf(zr[d], cr[d], acc);
      float dist = (znorm - 2.0f * acc) + cnorm[k];
      if (dist < bd) { bd = dist; bk = k; }
    }
#pragma unroll
    for (int m = 1; m < 64; m <<= 1) {
      float od = __shfl_xor(bd, m, 64);
      int ok = __shfl_xor(bk, m, 64);
      if (od < bd || (od == bd && ok < bk)) { bd = od; bk = ok; }
    }

    if (bk != kold) {
      const float* cr = cb + (size_t)bk * DDIM;
#pragma unroll
      for (int i = 0; i < 4; ++i) {
        int d0 = lane + i * 64;
        float zd = zr[d0], cd = cr[d0];
        out[(size_t)row * DDIM + d0] = zd + (cd - zd);
      }
    }
    if (lane == 0) out[OFF_IDX + row] = (float)bk;
  }
}

// ---- MFMA main v5 (r10 verified) — fallback if ws too small for logits ----
__global__ __launch_bounds__(1024, 4) void vq_main5(const float* __restrict__ z,
                                                    const float* __restrict__ cb,
                                                    const unsigned short* __restrict__ img,
                                                    float* __restrict__ out,
                                                    float* __restrict__ ws) {
  __shared__ __align__(16) unsigned char smem[102656];
  float* pacc = (float*)smem;
  unsigned short* zh_s = (unsigned short*)(smem + 4096);
  unsigned short* zl_s = (unsigned short*)(smem + 20480);
  float* logits = (float*)(smem + 36864);
  float* redH = (float*)(smem + 102400);
  float* redS = (float*)(smem + 102464);

  const int tid = threadIdx.x;
  const int w = tid >> 6;
  const int lane = tid & 63;
  const int l31 = lane & 31, lhi = lane >> 5;
  const float* cnorm = ws + 1026;
  const int ct0 = w * 2, ct1 = w * 2 + 1;
  const unsigned short* pw = img + lane * 8;
  const float cn0 = cnorm[ct0 * 32 + l31];
  const float cn1 = cnorm[ct1 * 32 + l31];
  const int erow = tid >> 6, ecl = tid & 63;

  pacc[tid] = 0.0f;
  float hacc = 0.0f, sqacc = 0.0f;

#pragma unroll 1
  for (int t = 0; t < 4; ++t) {
    const int nbase = (blockIdx.x * 4 + t) * 32;
#pragma unroll
    for (int i = 0; i < 8; ++i) {
      int idx = tid + (i << 10);
      int row = idx >> 8, k = idx & 255;
      float x = z[((size_t)(nbase + row) << 8) + k];
      unsigned short hh, ll;
      bf16split(x, hh, ll);
      int uoff = (row << 8) | ((((k >> 3) ^ row) & 31) << 3) | (k & 7);
      zh_s[uoff] = hh; zl_s[uoff] = ll;
    }
    __syncthreads();

    f32x16 acc0, acc1;
#pragma unroll
    for (int e = 0; e < 16; ++e) { acc0[e] = 0.0f; acc1[e] = 0.0f; }

    const unsigned short* p0 = pw + ct0 * 1024;
    const unsigned short* p1 = pw + ct1 * 1024;
    bf16x8 nbh0 = *(const bf16x8*)(p0);
    bf16x8 nbl0 = *(const bf16x8*)(p0 + 512);
    bf16x8 nbh1 = *(const bf16x8*)(p1);
    bf16x8 nbl1 = *(const bf16x8*)(p1 + 512);
    int au0 = (l31 << 8) | (((lhi ^ l31) & 31) << 3);
    bf16x8 nazh = *(const bf16x8*)(zh_s + au0);
    bf16x8 nazl = *(const bf16x8*)(zl_s + au0);

#pragma unroll 1
    for (int kc = 0; kc < 16; ++kc) {
      bf16x8 ch0 = nbh0, cl0 = nbl0, ch1 = nbh1, cl1 = nbl1;
      bf16x8 cah = nazh, cal = nazl;
      const int kn = (kc + 1) & 15;
      const unsigned short* pk = pw + kn * 32768;
      const unsigned short* q0 = pk + ct0 * 1024;
      const unsigned short* q1 = pk + ct1 * 1024;
      nbh0 = *(const bf16x8*)(q0);
      nbl0 = *(const bf16x8*)(q0 + 512);
      nbh1 = *(const bf16x8*)(q1);
      nbl1 = *(const bf16x8*)(q1 + 512);
      const int aun = (l31 << 8) | (((((kn << 1) | lhi) ^ l31) & 31) << 3);
      nazh = *(const bf16x8*)(zh_s + aun);
      nazl = *(const bf16x8*)(zl_s + aun);
      acc0 = MFMA32(cah, ch0, acc0);
      acc1 = MFMA32(cah, ch1, acc1);
      acc0 = MFMA32(cah, cl0, acc0);
      acc1 = MFMA32(cah, cl1, acc1);
      acc0 = MFMA32(cal, ch0, acc0);
      acc1 = MFMA32(cal, ch1, acc1);
    }

#pragma unroll
    for (int g = 0; g < 2; ++g) {
      __syncthreads();
#pragma unroll
      for (int q = 0; q < 8; ++q) {
        int reg = q + (g << 3);
        int r16 = (q & 3) | ((q >> 2) << 3) | (lhi << 2);
        logits[(r16 << 10) + ct0 * 32 + l31] = 200.0f * acc0[reg] - 100.0f * cn0;
        logits[(r16 << 10) + ct1 * 32 + l31] = 200.0f * acc1[reg] - 100.0f * cn1;
      }
      __syncthreads();
      const int grow = nbase + (g << 4) + erow;
      float v2[16];
#pragma unroll
      for (int m = 0; m < 16; ++m) v2[m] = logits[(erow << 10) + ecl + (m << 6)];
      float m1 = -3.4e38f, m2v = -3.4e38f;
      int c1 = 0;
#pragma unroll
      for (int m = 0; m < 16; ++m) {
        float val = v2[m];
        if (val > m1) { m2v = m1; m1 = val; c1 = ecl + (m << 6); }
        else if (val > m2v) { m2v = val; }
      }
#pragma unroll
      for (int mk = 1; mk < 64; mk <<= 1) {
        float om1 = __shfl_xor(m1, mk, 64);
        int oc1 = __shfl_xor(c1, mk, 64);
        float om2 = __shfl_xor(m2v, mk, 64);
        if (om1 > m1 || (om1 == m1 && oc1 < c1)) { m2v = fmaxf(m1, om2); m1 = om1; c1 = oc1; }
        else { m2v = fmaxf(om1, m2v); }
      }
      const float rowmax = m1;
      const int bcol = c1;
      const bool danger = (m1 - m2v) < 0.25f;
      float S = 0.f, T = 0.f;
#pragma unroll
      for (int m = 0; m < 16; ++m) {
        float e = __expf(v2[m] - rowmax);
        S += e;
        T = fmaf(e, v2[m], T);
        v2[m] = e;
      }
#pragma unroll
      for (int mk = 1; mk < 64; mk <<= 1) {
        S += __shfl_xor(S, mk, 64);
        T += __shfl_xor(T, mk, 64);
      }
      const float invZ = 1.0f / S;
      const float H = rowmax + logf(S) - T * invZ;
#pragma unroll
      for (int m = 0; m < 16; ++m) atomicAdd(&pacc[ecl + (m << 6)], v2[m] * invZ);
      float sq = 0.f;
      {
        const float* zr = z + ((size_t)grow << 8) + (ecl << 2);
        const float* cr = cb + ((size_t)bcol << 8) + (ecl << 2);
        float* orow = out + ((size_t)grow << 8) + (ecl << 2);
        float4 zv = *(const float4*)(zr);
        float4 cv = *(const float4*)(cr);
        float4 qv;
        qv.x = zv.x + (cv.x - zv.x);
        qv.y = zv.y + (cv.y - zv.y);
        qv.z = zv.z + (cv.z - zv.z);
        qv.w = zv.w + (cv.w - zv.w);
        *(float4*)(orow) = qv;
        float dx = cv.x - zv.x; sq = fmaf(dx, dx, sq);
        dx = cv.y - zv.y; sq = fmaf(dx, dx, sq);
        dx = cv.z - zv.z; sq = fmaf(dx, dx, sq);
        dx = cv.w - zv.w; sq = fmaf(dx, dx, sq);
      }
#pragma unroll
      for (int mk = 1; mk < 64; mk <<= 1) sq += __shfl_xor(sq, mk, 64);
      if (ecl == 0) {
        hacc += H;
        sqacc += sq;
        out[OFF_IDX + grow] = danger ? -(float)(bcol + 1) : (float)bcol;
      }
    }
  }

  if (ecl == 0) { redH[erow] = hacc; redS[erow] = sqacc; }
  __syncthreads();
  atomicAdd(&ws[tid], pacc[tid]);
  if (tid == 0) {
    float hs = 0.f, ss = 0.f;
#pragma unroll
    for (int i = 0; i < 16; ++i) { hs += redH[i]; ss += redS[i]; }
    atomicAdd(&ws[1024], hs);
    atomicAdd(&ws[1025], ss);
  }
}

extern "C" void kernel_launch(void* const* d_in, const int* in_sizes, int n_in,
                              void* d_out, int out_size, void* d_ws, size_t ws_size,
                              hipStream_t stream) {
  const float* z = (const float*)d_in[0];
  const float* cb = (const float*)d_in[1];
  float* out = (float*)d_out;
  float* ws = (float*)d_ws;
  const unsigned short* img = (const unsigned short*)(ws + WS_IMG_F);

  vq_pre<<<192, 256, 0, stream>>>(cb, ws);

  size_t need = ((size_t)WL2_BASE_F + WL2_CAP + 64) * 4ull;
  if (ws_size >= need) {
    _Float16* lgbuf = (_Float16*)(ws + WS_LG_F);
    vq_gemm64<<<NROWS / 64, 1024, 0, stream>>>(z, img, lgbuf, ws, 0);
    vq_epi<<<1024, 256, 0, stream>>>(z, cb, lgbuf, out, ws, 0, NROWS);
    vq_fix2<<<256, 256, 0, stream>>>(z, cb, lgbuf, out, ws);
  } else {
    vq_main5<<<256, 1024, 0, stream>>>(z, cb, img, out, ws);
  }
  vq_fixfinal<<<257, 256, 0, stream>>>(z, cb, out, ws);
}